// Round 11
// baseline (733.331 us; speedup 1.0000x reference)
//
#include <hip/hip_runtime.h>

typedef __bf16 bf8 __attribute__((ext_vector_type(8)));
typedef float f4 __attribute__((ext_vector_type(4)));

// native bf16 store (compiler emits single-op converts; RNE)
__device__ __forceinline__ void stb(unsigned short* p, float v) { *(__bf16*)p = (__bf16)v; }

// async global->LDS, 16 bytes per lane; LDS dest = wave-uniform base + lane*16
__device__ __forceinline__ void gl_lds16(const unsigned short* g, unsigned short* l) {
  __builtin_amdgcn_global_load_lds((const __attribute__((address_space(1))) unsigned int*)g,
                                   (__attribute__((address_space(3))) unsigned int*)l,
                                   16, 0, 0);
}

// cheap GELU, exp2-folded constants + hardware rcp.
__device__ __forceinline__ float gelu_fast(float v) {
  float w = v * v;
  float u = v * (-2.30222655f - 0.10294296f * w);
  float e = __builtin_amdgcn_exp2f(u);
  return v * __builtin_amdgcn_rcpf(1.0f + e);
}

// ---------------- weight transpose+cast: f32 [K,N] -> bf16 [N,K] ----------------
__global__ void transpose_kernel(const float* __restrict__ in,
                                 unsigned short* __restrict__ out, int K, int N) {
  int idx = blockIdx.x * 256 + threadIdx.x;
  if (idx < K * N) {
    int n = idx / K, k = idx - n * K;
    stb(&out[idx], in[k * N + n]);
  }
}

// ---------------- LayerNorm: C=192, one wave per token, f32 in -> bf16 out ----------------
__global__ __launch_bounds__(256) void ln_kernel(const float* __restrict__ xin,
                                                 const float* __restrict__ g,
                                                 const float* __restrict__ bb,
                                                 unsigned short* __restrict__ out) {
  long token = (long)blockIdx.x * 4 + (threadIdx.x >> 6);
  int lane = threadIdx.x & 63;
  const float* row = xin + token * 192;
  float v[3] = {row[lane], row[lane + 64], row[lane + 128]};
  float s = v[0] + v[1] + v[2];
#pragma unroll
  for (int m = 1; m < 64; m <<= 1) s += __shfl_xor(s, m, 64);
  float mean = s * (1.0f / 192.0f);
  float d0 = v[0] - mean, d1 = v[1] - mean, d2 = v[2] - mean;
  float dd = d0 * d0 + d1 * d1 + d2 * d2;
#pragma unroll
  for (int m = 1; m < 64; m <<= 1) dd += __shfl_xor(dd, m, 64);
  float rstd = rsqrtf(dd * (1.0f / 192.0f) + 1e-5f);
  unsigned short* orow = out + token * 192;
#pragma unroll
  for (int i = 0; i < 3; i++) {
    int c = lane + i * 64;
    stb(&orow[c], (v[i] - mean) * rstd * g[c] + bb[c]);
  }
}

// ---------------- MFMA GEMM: out = A[M,K](bf16) @ Bt[N,K]^T(bf16) + bias(f32) ----------------
// BM=128, BN=64, BK=64, 256 threads (4 waves), double-buffered LDS,
// global_load_lds width-16 staging + XOR chunk swizzle, counted vmcnt(6),
// XCD-chunked tile remap (round-6 structure, best measured).
template <int EPI>
__global__ __launch_bounds__(256) void gemm_kernel(const unsigned short* __restrict__ A,
                                                   const unsigned short* __restrict__ Bt,
                                                   const float* __restrict__ bias,
                                                   const float* __restrict__ res,
                                                   void* __restrict__ out, int K, int N) {
  __shared__ __align__(16) unsigned short As[2][128 * 64];
  __shared__ __align__(16) unsigned short Bs[2][64 * 64];
  const int tid = threadIdx.x;
  const int wave = tid >> 6;
  const int lane = tid & 63;
  const int quad = lane >> 4;
  const int l16 = lane & 15;

  const int NX = gridDim.x;
  int lin = blockIdx.y * NX + blockIdx.x;
  const int T = NX * gridDim.y;
  if ((T & 7) == 0) {
    lin = (lin & 7) * (T >> 3) + (lin >> 3);
  }
  const int bx = lin % NX;
  const int by = lin / NX;
  const long m0 = (long)by * 128;
  const long n0 = (long)bx * 64;

  long a_src[4];
  int a_dstc[4];
#pragma unroll
  for (int j = 0; j < 4; ++j) {
    int L = (wave * 4 + j) * 64 + lane;
    int row = L >> 3, cs = L & 7;
    a_src[j] = (m0 + row) * (long)K + ((cs ^ (row & 7)) << 3);
    a_dstc[j] = (wave * 4 + j) * 512;
  }
  long b_src[2];
  int b_dstc[2];
#pragma unroll
  for (int j = 0; j < 2; ++j) {
    int L = (wave * 2 + j) * 64 + lane;
    int row = L >> 3, cs = L & 7;
    b_src[j] = (n0 + row) * (long)K + ((cs ^ (row & 7)) << 3);
    b_dstc[j] = (wave * 2 + j) * 512;
  }

  const int nT = K >> 6;
  f4 acc[2][4] = {};

#pragma unroll
  for (int j = 0; j < 4; ++j) gl_lds16(A + a_src[j], &As[0][a_dstc[j]]);
#pragma unroll
  for (int j = 0; j < 2; ++j) gl_lds16(Bt + b_src[j], &Bs[0][b_dstc[j]]);

  int cur = 0;
  for (int t = 0; t < nT; ++t) {
    if (t + 1 < nT) {
      const int k0 = (t + 1) << 6;
#pragma unroll
      for (int j = 0; j < 4; ++j) gl_lds16(A + a_src[j] + k0, &As[cur ^ 1][a_dstc[j]]);
#pragma unroll
      for (int j = 0; j < 2; ++j) gl_lds16(Bt + b_src[j] + k0, &Bs[cur ^ 1][b_dstc[j]]);
      asm volatile("s_waitcnt vmcnt(6)" ::: "memory");
    } else {
      asm volatile("s_waitcnt vmcnt(0)" ::: "memory");
    }
    __builtin_amdgcn_s_barrier();
    __builtin_amdgcn_sched_barrier(0);
#pragma unroll
    for (int kk = 0; kk < 2; ++kk) {
      bf8 a[2], b[4];
#pragma unroll
      for (int mt = 0; mt < 2; ++mt) {
        int r = wave * 32 + mt * 16 + l16;
        int c = kk * 4 + quad;
        a[mt] = *(const bf8*)&As[cur][r * 64 + ((c ^ (r & 7)) << 3)];
      }
#pragma unroll
      for (int nt = 0; nt < 4; ++nt) {
        int r = nt * 16 + l16;
        int c = kk * 4 + quad;
        b[nt] = *(const bf8*)&Bs[cur][r * 64 + ((c ^ (r & 7)) << 3)];
      }
#pragma unroll
      for (int mt = 0; mt < 2; ++mt)
#pragma unroll
        for (int nt = 0; nt < 4; ++nt)
          acc[mt][nt] = __builtin_amdgcn_mfma_f32_16x16x32_bf16(a[mt], b[nt], acc[mt][nt], 0, 0, 0);
    }
    __builtin_amdgcn_sched_barrier(0);
    __builtin_amdgcn_s_barrier();
    cur ^= 1;
  }

#pragma unroll
  for (int nt = 0; nt < 4; ++nt) {
    long n = n0 + nt * 16 + l16;
    float bv = bias[n];
#pragma unroll
    for (int mt = 0; mt < 2; ++mt) {
#pragma unroll
      for (int r = 0; r < 4; ++r) {
        long m = m0 + wave * 32 + mt * 16 + quad * 4 + r;
        float v = acc[mt][nt][r] + bv;
        long idx = m * N + n;
        if (EPI == 0) {
          stb(&((unsigned short*)out)[idx], v);
        } else if (EPI == 2) {
          stb(&((unsigned short*)out)[idx], gelu_fast(v));
        } else {
          ((float*)out)[idx] = v + res[idx];
        }
      }
    }
  }
}

// ---------------- fused proj GEMM + residual + LayerNorm2 ----------------
// BM=128, BN=192 (full row), BK=64, K=192, 256 threads (4 waves), grid (1, 784).
__global__ __launch_bounds__(256) void proj_ln_kernel(const unsigned short* __restrict__ A,
                                                      const unsigned short* __restrict__ Bt,
                                                      const float* __restrict__ bias,
                                                      const float* __restrict__ res,
                                                      const float* __restrict__ g2,
                                                      const float* __restrict__ b2,
                                                      float* __restrict__ xres,
                                                      unsigned short* __restrict__ lnout) {
  __shared__ __align__(16) unsigned short As[2][128 * 64];
  __shared__ __align__(16) unsigned short Bs[2][192 * 64];
  const int tid = threadIdx.x;
  const int wave = tid >> 6;
  const int lane = tid & 63;
  const int quad = lane >> 4;
  const int l16 = lane & 15;

  int lin = blockIdx.y;
  const int T = gridDim.y;
  if ((T & 7) == 0) lin = (lin & 7) * (T >> 3) + (lin >> 3);
  const long m0 = (long)lin * 128;

  long a_src[4];
  int a_dstc[4];
#pragma unroll
  for (int j = 0; j < 4; ++j) {
    int L = (wave * 4 + j) * 64 + lane;
    int row = L >> 3, cs = L & 7;
    a_src[j] = (m0 + row) * 192L + ((cs ^ (row & 7)) << 3);
    a_dstc[j] = (wave * 4 + j) * 512;
  }
  long b_src[6];
  int b_dstc[6];
#pragma unroll
  for (int j = 0; j < 6; ++j) {
    int L = (wave * 6 + j) * 64 + lane;
    int row = L >> 3, cs = L & 7;
    b_src[j] = row * 192L + ((cs ^ (row & 7)) << 3);
    b_dstc[j] = (wave * 6 + j) * 512;
  }

  f4 acc[2][12] = {};

#pragma unroll
  for (int j = 0; j < 4; ++j) gl_lds16(A + a_src[j], &As[0][a_dstc[j]]);
#pragma unroll
  for (int j = 0; j < 6; ++j) gl_lds16(Bt + b_src[j], &Bs[0][b_dstc[j]]);

  int cur = 0;
  for (int t = 0; t < 3; ++t) {
    if (t + 1 < 3) {
      const int k0 = (t + 1) << 6;
#pragma unroll
      for (int j = 0; j < 4; ++j) gl_lds16(A + a_src[j] + k0, &As[cur ^ 1][a_dstc[j]]);
#pragma unroll
      for (int j = 0; j < 6; ++j) gl_lds16(Bt + b_src[j] + k0, &Bs[cur ^ 1][b_dstc[j]]);
      asm volatile("s_waitcnt vmcnt(10)" ::: "memory");
    } else {
      asm volatile("s_waitcnt vmcnt(0)" ::: "memory");
    }
    __builtin_amdgcn_s_barrier();
    __builtin_amdgcn_sched_barrier(0);
#pragma unroll
    for (int kk = 0; kk < 2; ++kk) {
      bf8 a[2];
#pragma unroll
      for (int mt = 0; mt < 2; ++mt) {
        int r = wave * 32 + mt * 16 + l16;
        int c = kk * 4 + quad;
        a[mt] = *(const bf8*)&As[cur][r * 64 + ((c ^ (r & 7)) << 3)];
      }
#pragma unroll
      for (int nt = 0; nt < 12; ++nt) {
        int r = nt * 16 + l16;
        int c = kk * 4 + quad;
        bf8 b = *(const bf8*)&Bs[cur][r * 64 + ((c ^ (r & 7)) << 3)];
#pragma unroll
        for (int mt = 0; mt < 2; ++mt)
          acc[mt][nt] = __builtin_amdgcn_mfma_f32_16x16x32_bf16(a[mt], b, acc[mt][nt], 0, 0, 0);
      }
    }
    __builtin_amdgcn_sched_barrier(0);
    __builtin_amdgcn_s_barrier();
    cur ^= 1;
  }

#pragma unroll
  for (int mt = 0; mt < 2; ++mt) {
#pragma unroll
    for (int r = 0; r < 4; ++r) {
      long mm = m0 + wave * 32 + mt * 16 + quad * 4 + r;
      const float* rrow = res + mm * 192;
      float v[12];
      float s = 0.0f;
#pragma unroll
      for (int nt = 0; nt < 12; ++nt) {
        int n = nt * 16 + l16;
        float t = acc[mt][nt][r] + bias[n] + rrow[n];
        v[nt] = t;
        s += t;
      }
#pragma unroll
      for (int m = 1; m < 16; m <<= 1) s += __shfl_xor(s, m, 64);
      float mean = s * (1.0f / 192.0f);
      float d = 0.0f;
#pragma unroll
      for (int nt = 0; nt < 12; ++nt) {
        float dd = v[nt] - mean;
        d += dd * dd;
      }
#pragma unroll
      for (int m = 1; m < 16; m <<= 1) d += __shfl_xor(d, m, 64);
      float rstd = rsqrtf(d * (1.0f / 192.0f) + 1e-5f);
      float* xrow = xres + mm * 192;
      unsigned short* lrow = lnout + mm * 192;
#pragma unroll
      for (int nt = 0; nt < 12; ++nt) {
        int n = nt * 16 + l16;
        xrow[n] = v[nt];
        stb(&lrow[n], (v[nt] - mean) * rstd * g2[n] + b2[n]);
      }
    }
  }
}

// ---------------- fused MLP v2: out = gelu(A @ W1^T + b1) @ W2^T + b2 + xres ----------------
// 256 threads (4 waves), BM=64 (wave w owns rows [w*16, w*16+16)).
// A: 6 bf8 register fragments per lane, loaded once (reused across all 4 chunks).
// B: SINGLE 192x64 LDS buffer (24 KB) with register-prefetch: next tile's
// 6x16B/thread loaded global->reg during current stage's MFMAs, ds_write after
// the post-compute barrier. G: per-wave LDS [16][200] (25.6 KB).
// Total LDS ~50 KB -> 3 blocks/CU = 12 waves/CU (vs round-10's 1 block/CU).
__global__ __launch_bounds__(256, 3) void mlp_kernel(const unsigned short* __restrict__ A,    // LN2 out bf16 [M,192]
                                                     const unsigned short* __restrict__ W1t,  // [768,192] bf16
                                                     const unsigned short* __restrict__ W2t,  // [192,768] bf16
                                                     const float* __restrict__ b1,
                                                     const float* __restrict__ b2,
                                                     const float* __restrict__ res,           // xres f32 [M,192]
                                                     float* __restrict__ out) {               // [M,192] f32
  __shared__ __align__(16) unsigned short Bs[192 * 64];     // 24 KB, single buffer
  __shared__ __align__(16) unsigned short Gs[4][16 * 200];  // 25.6 KB
  const int tid = threadIdx.x;
  const int wave = tid >> 6;   // 0..3
  const int lane = tid & 63;
  const int quad = lane >> 4;
  const int l16 = lane & 15;

  int lin = blockIdx.x;
  const int T = gridDim.x;
  if ((T & 7) == 0) lin = (lin & 7) * (T >> 3) + (lin >> 3);
  const long m0 = (long)lin * 64;

  // ---- A row fragments: lane (l16,quad) holds row m0+wave*16+l16, cols s*32+quad*8 ----
  const long arow = (m0 + wave * 16 + l16) * 192 + quad * 8;
  bf8 afrag[6];
#pragma unroll
  for (int s = 0; s < 6; ++s) afrag[s] = *(const bf8*)(A + arow + s * 32);

  // ---- B reg-prefetch: 192 rows x 8 chunks = 1536 chunks, 6 per thread ----
  uint4 breg[6];
  // load tile (c_, p_, kb_) into breg
#define BLOAD(c_, p_, kb_)                                                      \
  {                                                                             \
    _Pragma("unroll") for (int j = 0; j < 6; ++j) {                             \
      int L = j * 256 + tid;                                                    \
      int row = L >> 3, cs = L & 7;                                             \
      long src_;                                                                \
      if ((p_) == 0)                                                            \
        src_ = ((long)(c_) * 192 + row) * 192 + (kb_) * 64 + ((cs ^ (row & 7)) << 3); \
      else                                                                      \
        src_ = (long)row * 768 + (c_) * 192 + (kb_) * 64 + ((cs ^ (row & 7)) << 3);   \
      breg[j] = *(const uint4*)(((p_) == 0 ? W1t : W2t) + src_);                \
    }                                                                           \
  }
#define BWRITE()                                                                \
  {                                                                             \
    _Pragma("unroll") for (int j = 0; j < 6; ++j) {                             \
      int L = j * 256 + tid;                                                    \
      *(uint4*)&Bs[L * 8] = breg[j];                                            \
    }                                                                           \
  }

  f4 oacc[12] = {};
  const int swzl = l16 & 7;
  unsigned short* Gmy = &Gs[wave][0];

  // prologue: stage (c=0, p=0, kb=0) into Bs
  BLOAD(0, 0, 0);
  asm volatile("s_waitcnt vmcnt(0)" ::: "memory");
  BWRITE();
  asm volatile("s_waitcnt lgkmcnt(0)" ::: "memory");
  __builtin_amdgcn_s_barrier();
  __builtin_amdgcn_sched_barrier(0);

#pragma unroll 1
  for (int c = 0; c < 4; ++c) {
    f4 gacc[12] = {};
    // ---- fc1 phase: 3 stages ----
#pragma unroll 1
    for (int kb = 0; kb < 3; ++kb) {
      if (kb < 2) { BLOAD(c, 0, kb + 1); } else { BLOAD(c, 1, 0); }
#pragma unroll
      for (int kk = 0; kk < 2; ++kk) {
        bf8 a = afrag[kb * 2 + kk];
#pragma unroll
        for (int nt = 0; nt < 12; ++nt) {
          bf8 b = *(const bf8*)&Bs[(nt * 16 + l16) * 64 + (((kk * 4 + quad) ^ swzl) << 3)];
          gacc[nt] = __builtin_amdgcn_mfma_f32_16x16x32_bf16(a, b, gacc[nt], 0, 0, 0);
        }
      }
      __builtin_amdgcn_sched_barrier(0);
      __builtin_amdgcn_s_barrier();        // all waves done reading Bs
      asm volatile("s_waitcnt vmcnt(0)" ::: "memory");  // prefetch regs arrived
      BWRITE();
      asm volatile("s_waitcnt lgkmcnt(0)" ::: "memory");
      __builtin_amdgcn_s_barrier();        // new tile visible
      __builtin_amdgcn_sched_barrier(0);
    }
    // ---- GELU -> per-wave G (private; no cross-wave sync) ----
#pragma unroll
    for (int nt = 0; nt < 12; ++nt) {
      float bv = b1[c * 192 + nt * 16 + l16];
#pragma unroll
      for (int r = 0; r < 4; ++r) {
        float g = gelu_fast(gacc[nt][r] + bv);
        stb(&Gmy[(quad * 4 + r) * 200 + nt * 16 + l16], g);
      }
    }
    asm volatile("s_waitcnt lgkmcnt(0)" ::: "memory");
    __builtin_amdgcn_sched_barrier(0);
    // ---- fc2 phase: 3 stages ----
#pragma unroll 1
    for (int kb = 0; kb < 3; ++kb) {
      const bool has_next = (kb < 2) || (c < 3);
      if (kb < 2) { BLOAD(c, 1, kb + 1); }
      else if (c < 3) { BLOAD(c + 1, 0, 0); }
#pragma unroll
      for (int kk = 0; kk < 2; ++kk) {
        bf8 a = *(const bf8*)&Gmy[l16 * 200 + (kb * 2 + kk) * 32 + quad * 8];
#pragma unroll
        for (int nt = 0; nt < 12; ++nt) {
          bf8 b = *(const bf8*)&Bs[(nt * 16 + l16) * 64 + (((kk * 4 + quad) ^ swzl) << 3)];
          oacc[nt] = __builtin_amdgcn_mfma_f32_16x16x32_bf16(a, b, oacc[nt], 0, 0, 0);
        }
      }
      __builtin_amdgcn_sched_barrier(0);
      __builtin_amdgcn_s_barrier();
      if (has_next) {
        asm volatile("s_waitcnt vmcnt(0)" ::: "memory");
        BWRITE();
        asm volatile("s_waitcnt lgkmcnt(0)" ::: "memory");
      }
      __builtin_amdgcn_s_barrier();
      __builtin_amdgcn_sched_barrier(0);
    }
  }
#undef BLOAD
#undef BWRITE

  // ---- epilogue: + b2 + xres -> f32 out ----
#pragma unroll
  for (int r = 0; r < 4; ++r) {
    long mm = m0 + wave * 16 + quad * 4 + r;
    const float* rrow = res + mm * 192;
    float* orow = out + mm * 192;
#pragma unroll
    for (int nt = 0; nt < 12; ++nt) {
      int n = nt * 16 + l16;
      orow[n] = oacc[nt][r] + b2[n] + rrow[n];
    }
  }
}

// ---------------- MFMA shifted-window attention ----------------
__global__ __launch_bounds__(128) void attn_kernel(const unsigned short* __restrict__ qkv,
                                                   const float* __restrict__ rel_t,
                                                   unsigned short* __restrict__ o) {
  __shared__ __align__(16) unsigned short sh[2 * 6912];
  __shared__ float relh[2][170];
  __shared__ int toksh[2][49];
  __shared__ int zsh[2][49];
  const int wave = threadIdx.x >> 6;
  const int lane = threadIdx.x & 63;
  const int quad = lane >> 4;
  const int l16 = lane & 15;
  const int p = blockIdx.x * 2 + wave;
  const int head = p % 6;
  const int wib = p / 6;
  const int wi = wib & 63;
  const int b = wib >> 6;
  unsigned short* Vts = sh + wave * 6912;
  unsigned short* Ps = Vts + 2304;

  if (lane < 49) {
    int r = lane / 7, c = lane - (lane / 7) * 7;
    int ph = (wi >> 3) * 7 + r, pw = (wi & 7) * 7 + c;
    int h = ph + 3; if (h >= 56) h -= 56;
    int w = pw + 3; if (w >= 56) w -= 56;
    toksh[wave][lane] = (b * 56 + h) * 56 + w;
    int zh = (ph < 49) ? 0 : (ph < 53 ? 1 : 2);
    int zw = (pw < 49) ? 0 : (pw < 53 ? 1 : 2);
    zsh[wave][lane] = zh * 3 + zw;
  }
  for (int i = lane; i < 169; i += 64) relh[wave][i] = rel_t[i * 6 + head];
  {
#pragma unroll
    for (int e = 0; e < 4; e++) {
      int ee = lane + e * 64;
      int d = ee >> 3, c8 = ee & 7;
      *(unsigned int*)&Vts[d * 72 + 48 + c8 * 2] = 0u;
    }
  }
  __syncthreads();

  for (int e = lane; e < 196; e += 64) {
    int n = e >> 2, c = e & 3;
    int t = toksh[wave][n];
    uint4 vc = *(const uint4*)(qkv + (long)t * 576 + head * 32 + 384 + c * 8);
    const unsigned short* vv = (const unsigned short*)&vc;
#pragma unroll
    for (int j = 0; j < 8; j++) Vts[(c * 8 + j) * 72 + n] = vv[j];
  }

  bf8 zv;
#pragma unroll
  for (int q8 = 0; q8 < 8; q8++) zv[q8] = (__bf16)0.0f;
  bf8 af[4], bf_[4];
#pragma unroll
  for (int i = 0; i < 4; i++) {
    int row = 16 * i + l16;
    int rv = row < 49 ? row : 48;
    long base = (long)toksh[wave][rv] * 576 + head * 32 + quad * 8;
    bf8 qf = *(const bf8*)(qkv + base);
    bf8 kf = *(const bf8*)(qkv + base + 192);
    if (row >= 49) { qf = zv; kf = zv; }
    af[i] = qf;
    bf_[i] = kf;
  }

  f4 S[4][4];
#pragma unroll
  for (int i = 0; i < 4; i++)
#pragma unroll
    for (int j = 0; j < 4; j++)
      S[i][j] = __builtin_amdgcn_mfma_f32_16x16x32_bf16(af[i], bf_[j], (f4){0.f, 0.f, 0.f, 0.f}, 0, 0, 0);

  int colv[4], colkey[4], zcol[4];
#pragma unroll
  for (int jt = 0; jt < 4; jt++) {
    int col = 16 * jt + l16;
    int cc = col < 49 ? col : 48;
    int rj = cc / 7, cj = cc - rj * 7;
    colkey[jt] = rj * 13 + cj;
    zcol[jt] = zsh[wave][cc];
    colv[jt] = (col < 49);
  }

  __syncthreads();

  const float sc = 0.17677669529663687f;  // 1/sqrt(32)
#pragma unroll
  for (int it = 0; it < 4; it++) {
#pragma unroll
    for (int r = 0; r < 4; r++) {
      int row = 16 * it + quad * 4 + r;
      int row2 = row < 49 ? row : 48;
      int ri = row2 / 7, ci = row2 - ri * 7;
      int rk = ri * 13 + ci + 84;
      int zr = zsh[wave][row2];
      float v[4];
#pragma unroll
      for (int jt = 0; jt < 4; jt++) {
        float bias = relh[wave][rk - colkey[jt]];
        float msk = (zr == zcol[jt]) ? 0.0f : -100.0f;
        float val = S[it][jt][r] * sc + bias + msk;
        v[jt] = colv[jt] ? val : -1e30f;
      }
      float mx = fmaxf(fmaxf(v[0], v[1]), fmaxf(v[2], v[3]));
#pragma unroll
      for (int m = 1; m < 16; m <<= 1) mx = fmaxf(mx, __shfl_xor(mx, m, 64));
      float e0 = __expf(v[0] - mx), e1 = __expf(v[1] - mx), e2 = __expf(v[2] - mx), e3 = __expf(v[3] - mx);
      float sum = e0 + e1 + e2 + e3;
#pragma unroll
      for (int m = 1; m < 16; m <<= 1) sum += __shfl_xor(sum, m, 64);
      float inv = 1.0f / sum;
      stb(&Ps[row * 72 + 0 + l16], e0 * inv);
      stb(&Ps[row * 72 + 16 + l16], e1 * inv);
      stb(&Ps[row * 72 + 32 + l16], e2 * inv);
      stb(&Ps[row * 72 + 48 + l16], e3 * inv);
    }
  }
  __syncthreads();

  f4 O[4][2] = {};
#pragma unroll
  for (int ks = 0; ks < 2; ks++) {
    bf8 pv[2];
#pragma unroll
    for (int nt = 0; nt < 2; nt++) pv[nt] = *(const bf8*)&Vts[(16 * nt + l16) * 72 + ks * 32 + quad * 8];
#pragma unroll
    for (int mt = 0; mt < 4; mt++) {
      bf8 pa = *(const bf8*)&Ps[(16 * mt + l16) * 72 + ks * 32 + quad * 8];
#pragma unroll
      for (int nt = 0; nt < 2; nt++)
        O[mt][nt] = __builtin_amdgcn_mfma_f32_16x16x32_bf16(pa, pv[nt], O[mt][nt], 0, 0, 0);
    }
  }
#pragma unroll
  for (int mt = 0; mt < 4; mt++) {
#pragma unroll
    for (int r = 0; r < 4; r++) {
      int row = 16 * mt + quad * 4 + r;
      if (row < 49) {
        long base = (long)toksh[wave][row] * 192 + head * 32 + l16;
        stb(&o[base], O[mt][0][r]);
        stb(&o[base + 16], O[mt][1][r]);
      }
    }
  }
}

extern "C" void kernel_launch(void* const* d_in, const int* in_sizes, int n_in,
                              void* d_out, int out_size, void* d_ws, size_t ws_size,
                              hipStream_t stream) {
  const float* x      = (const float*)d_in[0];
  const float* n1g    = (const float*)d_in[1];
  const float* n1b    = (const float*)d_in[2];
  const float* qkv_w  = (const float*)d_in[3];
  const float* qkv_b  = (const float*)d_in[4];
  const float* proj_w = (const float*)d_in[5];
  const float* proj_b = (const float*)d_in[6];
  const float* n2g    = (const float*)d_in[7];
  const float* n2b    = (const float*)d_in[8];
  const float* fc1_w  = (const float*)d_in[9];
  const float* fc1_b  = (const float*)d_in[10];
  const float* fc2_w  = (const float*)d_in[11];
  const float* fc2_b  = (const float*)d_in[12];
  const float* rel_t  = (const float*)d_in[13];
  const float* mask   = (const float*)d_in[15];
  (void)mask;

  char* ws = (char*)d_ws;
  unsigned short* qkv_wT  = (unsigned short*)(ws + 0);          // 576x192 bf16
  unsigned short* proj_wT = (unsigned short*)(ws + 221184);     // 192x192
  unsigned short* fc1_wT  = (unsigned short*)(ws + 294912);     // 768x192
  unsigned short* fc2_wT  = (unsigned short*)(ws + 589824);     // 192x768
  unsigned short* bufA    = (unsigned short*)(ws + 884736);     // 100352x192 bf16
  unsigned short* bufB    = (unsigned short*)(ws + 39419904ULL);// 100352x576 bf16
  float*          xres    = (float*)(ws + 193560576ULL);        // 100352x192 f32

  const int M = 100352;  // 32 * 56 * 56

  transpose_kernel<<<(192 * 576 + 255) / 256, 256, 0, stream>>>(qkv_w, qkv_wT, 192, 576);
  transpose_kernel<<<(192 * 192 + 255) / 256, 256, 0, stream>>>(proj_w, proj_wT, 192, 192);
  transpose_kernel<<<(192 * 768 + 255) / 256, 256, 0, stream>>>(fc1_w, fc1_wT, 192, 768);
  transpose_kernel<<<(768 * 192 + 255) / 256, 256, 0, stream>>>(fc2_w, fc2_wT, 768, 192);

  ln_kernel<<<M / 4, 256, 0, stream>>>(x, n1g, n1b, bufA);
  gemm_kernel<0><<<dim3(576 / 64, M / 128), 256, 0, stream>>>(bufA, qkv_wT, qkv_b, nullptr, bufB, 192, 576);
  attn_kernel<<<12288 / 2, 128, 0, stream>>>(bufB, rel_t, bufA);
  proj_ln_kernel<<<dim3(1, M / 128), 256, 0, stream>>>(bufA, proj_wT, proj_b, x, n2g, n2b, xres, bufA);
  mlp_kernel<<<M / 64, 256, 0, stream>>>(bufA, fc1_wT, fc2_wT, fc1_b, fc2_b, xres, (float*)d_out);
}